// Round 6
// baseline (142.642 us; speedup 1.0000x reference)
//
#include <hip/hip_runtime.h>

// ---------- types ----------
typedef __attribute__((ext_vector_type(8))) __bf16 bf16x8;
typedef __attribute__((ext_vector_type(4))) float f32x4;
typedef __attribute__((ext_vector_type(16))) float f32x16;
typedef __attribute__((ext_vector_type(4))) unsigned short us4;
typedef __attribute__((ext_vector_type(4))) unsigned int u32x4;
typedef __attribute__((address_space(3))) void* as3vp;
typedef const __attribute__((address_space(1))) void* as1vp;

#define GLOAD_LDS16(g, l) __builtin_amdgcn_global_load_lds((as1vp)(g), (as3vp)(l), 16, 0, 0)

#if __has_builtin(__builtin_amdgcn_exp2f)
#define EXP2(x) __builtin_amdgcn_exp2f(x)
#else
#define EXP2(x) __expf((x) * 0.6931471805599453f)
#endif

__device__ __forceinline__ unsigned short f2bf(float f) {
  unsigned u = __builtin_bit_cast(unsigned, f);
  u += 0x7FFFu + ((u >> 16) & 1u);   // RNE
  return (unsigned short)(u >> 16);
}
__device__ __forceinline__ float bf2f(unsigned short u) {
  return __builtin_bit_cast(float, (unsigned)u << 16);
}
__device__ __forceinline__ unsigned int pkbf(float a, float b) {
  unsigned int r;
  asm("v_cvt_pk_bf16_f32 %0, %1, %2" : "=v"(r) : "v"(a), "v"(b));
  return r;
}

// ---------- f32 -> bf16 (vectorized) ----------
__global__ void cvt_f32_bf16(const float* __restrict__ x, unsigned short* __restrict__ y, int n4) {
  int i = blockIdx.x * 256 + threadIdx.x;
  if (i >= n4) return;
  float4 v = ((const float4*)x)[i];
  us4 o;
  o.x = f2bf(v.x); o.y = f2bf(v.y); o.z = f2bf(v.z); o.w = f2bf(v.w);
  ((us4*)y)[i] = o;
}

// ---------- W (KxN f32) -> WT (NxK bf16) ----------
__global__ void transpose_w_bf16(const float* __restrict__ W, unsigned short* __restrict__ WT,
                                 int K, int N) {
  __shared__ float t[32][33];
  const int tx = threadIdx.x & 31, ty = threadIdx.x >> 5;
  const int n0 = blockIdx.x * 32, k0 = blockIdx.y * 32;
#pragma unroll
  for (int i = 0; i < 32; i += 8)
    t[ty + i][tx] = W[(size_t)(k0 + ty + i) * N + n0 + tx];
  __syncthreads();
#pragma unroll
  for (int i = 0; i < 32; i += 8)
    WT[(size_t)(n0 + ty + i) * K + k0 + tx] = f2bf(t[tx][ty + i]);
}

// ---------- mask -> additive mask ----------
__global__ void mask2addm(const float* __restrict__ m, float* __restrict__ addm, int n) {
  int i = blockIdx.x * 256 + threadIdx.x;
  if (i < n) addm[i] = (m[i] != 0.f) ? 0.f : -1e30f;
}

// ---------- km[b,h,d] = sum_kv mask[b,kv] * K[b,kv,h*64+d]  (coalesced) ----------
__global__ void km_reduce(const unsigned short* __restrict__ Kbb, const float* __restrict__ mask,
                          float* __restrict__ km) {
  __shared__ float red[16][64];
  const int bh = blockIdx.x, b = bh >> 4;
  const int dg = (threadIdx.x & 15) * 4, rg = threadIdx.x >> 4;
  const unsigned short* kb = Kbb + (size_t)(b * 2048) * 1024 + (bh & 15) * 64 + dg;
  const float* mr = mask + b * 2048;
  float a0 = 0.f, a1 = 0.f, a2 = 0.f, a3 = 0.f;
#pragma unroll 4
  for (int kv = rg; kv < 2048; kv += 16) {
    const float mv = mr[kv];
    us4 kq = *(const us4*)(kb + (size_t)kv * 1024);
    a0 = fmaf(mv, bf2f(kq.x), a0); a1 = fmaf(mv, bf2f(kq.y), a1);
    a2 = fmaf(mv, bf2f(kq.z), a2); a3 = fmaf(mv, bf2f(kq.w), a3);
  }
  red[rg][dg] = a0; red[rg][dg + 1] = a1; red[rg][dg + 2] = a2; red[rg][dg + 3] = a3;
  __syncthreads();
  if (threadIdx.x < 64) {
    float s = 0.f;
#pragma unroll
    for (int i = 0; i < 16; ++i) s += red[i][threadIdx.x];
    km[bh * 64 + threadIdx.x] = s;
  }
}

// ---------- merged Q/K/V GEMM, 128x128 tile (m97 geometry), dbuf single-barrier ----------
// blockIdx.z: 0=Q (KDIM 1280, scaled 0.125*log2e), 1=K, 2=V (transposed epilogue).
__global__ __launch_bounds__(256, 2)
void gemm_all(const unsigned short* __restrict__ Aq,
              const unsigned short* __restrict__ Akv,
              const unsigned short* __restrict__ WqT,
              const unsigned short* __restrict__ WkT,
              const unsigned short* __restrict__ WvT,
              const float* __restrict__ bq,
              const float* __restrict__ bk,
              const float* __restrict__ bv,
              unsigned short* __restrict__ Qout,
              unsigned short* __restrict__ Kout,
              unsigned short* __restrict__ VTout) {
  __shared__ unsigned short sA[2][128 * 64];
  __shared__ unsigned short sB[2][128 * 64];
  const int z = blockIdx.z;
  const int KDIM = (z == 0) ? 1280 : 1024;
  const unsigned short* A = (z == 0) ? Aq : Akv;
  const unsigned short* Bt = (z == 0) ? WqT : ((z == 1) ? WkT : WvT);
  const float* bias = (z == 0) ? bq : ((z == 1) ? bk : bv);

  const int tid = threadIdx.x, lane = tid & 63, w = tid >> 6;
  const int l15 = lane & 15, lhi = lane >> 4;
  const int wm = w >> 1, wn = w & 1;
  const int row0 = blockIdx.x * 128, col0 = blockIdx.y * 128;

  const f32x4 zv = {0.f, 0.f, 0.f, 0.f};
  f32x4 acc[4][4];
#pragma unroll
  for (int m = 0; m < 4; ++m)
#pragma unroll
    for (int n = 0; n < 4; ++n) acc[m][n] = zv;

  auto stage = [&](int buf, int kt) {
#pragma unroll
    for (int i = 0; i < 4; ++i) {
      const int c = i * 256 + tid;                     // 0..1023
      const int r = c >> 3, kc = ((c & 7) ^ (r & 7)) * 8;
      GLOAD_LDS16(A + (size_t)(row0 + r) * KDIM + kt + kc, &sA[buf][0] + c * 8);
      GLOAD_LDS16(Bt + (size_t)(col0 + r) * KDIM + kt + kc, &sB[buf][0] + c * 8);
    }
  };

  const int NT = KDIM / 64;
  stage(0, 0);
  __syncthreads();
  int cur = 0;
  for (int t = 0; t < NT; ++t) {
    if (t + 1 < NT) stage(cur ^ 1, (t + 1) * 64);
    const unsigned short* sAb = &sA[cur][0];
    const unsigned short* sBb = &sB[cur][0];
#pragma unroll
    for (int ks = 0; ks < 2; ++ks) {
      const int koS = (ks * 32 + lhi * 8) ^ ((l15 & 7) * 8);
      bf16x8 af[4], bfr[4];
#pragma unroll
      for (int m = 0; m < 4; ++m) af[m] = *(const bf16x8*)(sAb + (wm * 64 + m * 16 + l15) * 64 + koS);
#pragma unroll
      for (int n = 0; n < 4; ++n) bfr[n] = *(const bf16x8*)(sBb + (wn * 64 + n * 16 + l15) * 64 + koS);
#pragma unroll
      for (int m = 0; m < 4; ++m)
#pragma unroll
        for (int n = 0; n < 4; ++n)
          acc[m][n] = __builtin_amdgcn_mfma_f32_16x16x32_bf16(af[m], bfr[n], acc[m][n], 0, 0, 0);
    }
    __syncthreads();
    cur ^= 1;
  }

  if (z <= 1) {
    unsigned short* C = (z == 0) ? Qout : Kout;
    const float scale = (z == 0) ? 0.18033688f : 1.0f;   // 0.125 * log2(e)
#pragma unroll
    for (int n = 0; n < 4; ++n) {
      const int gc = col0 + wn * 64 + n * 16 + l15;
      const float bb = bias[gc];
#pragma unroll
      for (int m = 0; m < 4; ++m) {
        const int gr0 = row0 + wm * 64 + m * 16 + lhi * 4;
#pragma unroll
        for (int r = 0; r < 4; ++r)
          C[(size_t)(gr0 + r) * 1024 + gc] = f2bf((acc[m][n][r] + bb) * scale);
      }
    }
  } else {
    // V: transpose 128(rows=sv) x 128(cols=ch) tile through LDS (swz5 XOR layout),
    // coalesced 16B stores into VT (B,H,64,SV).
    __syncthreads();
    unsigned short* tb = &sA[0][0];    // 128 cols x 64 u32-words = 32 KB
#pragma unroll
    for (int n = 0; n < 4; ++n) {
      const int gcL = wn * 64 + n * 16 + l15;          // 0..127
      const float bb = bias[col0 + gcL];
      const int swz = ((gcL & 7) << 2) | ((gcL >> 3) & 1);
#pragma unroll
      for (int m = 0; m < 4; ++m) {
#pragma unroll
        for (int k = 0; k < 2; ++k) {
          const int grPair = wm * 32 + m * 8 + lhi * 2 + k;   // 0..63
          const unsigned val = pkbf(acc[m][n][2 * k] + bb, acc[m][n][2 * k + 1] + bb);
          *(unsigned*)((char*)tb + gcL * 256 + ((grPair ^ swz) * 4)) = val;
        }
      }
    }
    __syncthreads();
    const int b_ = row0 >> 11;
#pragma unroll
    for (int it = 0; it < 8; ++it) {
      const int c = it * 256 + tid;    // 0..2047
      const int gcL = c >> 4, w0 = (c & 15) * 4;
      const int swz = ((gcL & 7) << 2) | ((gcL >> 3) & 1);
      u32x4 arr = *(const u32x4*)((const char*)tb + gcL * 256 + (((w0 ^ swz) & ~3) * 4));
      const int p = swz & 3;           // in {0,1}
      u32x4 o;
      o.x = arr[0 ^ p]; o.y = arr[1 ^ p]; o.z = arr[2 ^ p]; o.w = arr[3 ^ p];
      const int ch = col0 + gcL;
      *(u32x4*)(VTout + (((size_t)(b_ * 16 + (ch >> 6))) << 17) + (size_t)(ch & 63) * 2048 +
                (row0 & 2047) + w0 * 2) = o;
    }
  }
}

// ---------- fused flash attention + pooled gate + blend (split-KV x2) ----------
// 512 blocks (XCD-swizzled bh), 512 threads = 8 waves: qg = w&3 (32 q-rows),
// half = w>>2 (even/odd KV tiles, own dbuf stream). 16 waves/CU.
// Swapped-operand 32x32x16 MFMA, in-register softmax (log2 domain), addm as
// MFMA C-init, km.Q pooled gate, end-merge of the two halves via LDS.
__global__ __launch_bounds__(512, 4)
void attn_fused(const unsigned short* __restrict__ Q,   // (B*SQ,1024) bf16, 0.125*log2e scaled
                const unsigned short* __restrict__ Kb,  // (B*SV,1024) bf16
                const unsigned short* __restrict__ VT,  // (B,H,64,SV) bf16
                const float* __restrict__ addm_g,       // (B,SV) 0/-1e30
                const float* __restrict__ km,           // (B,H,64)
                const float* __restrict__ counts,       // (B)
                const float* __restrict__ gain,         // (H)
                const float* __restrict__ gbias,        // (H)
                const float* __restrict__ pq,           // (B*SQ,1280) f32
                float* __restrict__ out) {              // (B*SQ,1280) f32
  __shared__ __align__(16) char smem[73728];
  unsigned short* sK = (unsigned short*)smem;            // [half][dbuf][64*64] 32 KB
  unsigned short* sV = (unsigned short*)(smem + 32768);  // [half][dbuf][64*64] 32 KB
  float* saddm = (float*)(smem + 65536);                 // [2048] 8 KB
  float* sOT = (float*)smem;                             // epilogue overlay (32 KB)
  float* ex  = (float*)(smem + 65536);                   // merge exchange overlay (4 KB)

  const int tid = threadIdx.x, lane = tid & 63, w = tid >> 6;
  const int l31 = lane & 31, h5 = lane >> 5;
  const int qg = w & 3, half = w >> 2;
  const int f = blockIdx.x;
  const int qt = (f >> 3) & 15;
  const int bh = (f & 7) + 8 * (f >> 7);
  const int b = bh >> 4, hh = bh & 15;
  const int q0 = qt * 128;

  // stage additive mask (2048 f32, 512 threads x 16B)
  GLOAD_LDS16(addm_g + b * 2048 + tid * 4, (char*)saddm + tid * 16);

  // Q fragments (B-operand): lane l31 = q col, k = ks*16 + h5*8 + j
  bf16x8 qf[4];
  {
    const unsigned short* qp = Q + (size_t)(b * 2048 + q0 + qg * 32 + l31) * 1024 + hh * 64 + h5 * 8;
#pragma unroll
    for (int ks = 0; ks < 4; ++ks) qf[ks] = *(const bf16x8*)(qp + ks * 16);
  }

  // pooled = km . q (log2-scaled; corrected by ln2 in the gate)
  float pl_s = 0.f;
  {
    const float* kmp = km + (b * 16 + hh) * 64 + h5 * 8;
#pragma unroll
    for (int ks = 0; ks < 4; ++ks) {
      f32x4 ka = *(const f32x4*)(kmp + ks * 16);
      f32x4 kb4 = *(const f32x4*)(kmp + ks * 16 + 4);
#pragma unroll
      for (int j = 0; j < 4; ++j)
        pl_s += (float)qf[ks][j] * ka[j] + (float)qf[ks][j + 4] * kb4[j];
    }
    float ta = pl_s, tb = pl_s;
    asm("v_permlane32_swap_b32 %0, %1" : "+v"(ta), "+v"(tb));
    pl_s = ta + tb;
  }

  const unsigned short* Kbase = Kb + (size_t)(b * 2048) * 1024 + hh * 64;
  const unsigned short* Vbase = VT + (((size_t)(b * 16 + hh)) << 17);

  f32x16 o0, o1, l_vec;
#pragma unroll
  for (int r = 0; r < 16; ++r) { o0[r] = 0.f; o1[r] = 0.f; l_vec[r] = 0.f; }
  float m_ = -1e30f;

  const int vtid = qg * 64 + lane;   // 0..255 within this half
  auto stage = [&](int buf, int kv) {
#pragma unroll
    for (int i = 0; i < 2; ++i) {
      const int c = i * 256 + vtid;                    // 0..511
      const int r = c >> 3, sl = (c & 7) ^ (r & 7);
      const int dst = half * 16384 + buf * 8192 + c * 16;
      GLOAD_LDS16(Kbase + (size_t)(kv + r) * 1024 + sl * 8, (char*)sK + dst);
      GLOAD_LDS16(Vbase + (size_t)r * 2048 + kv + sl * 8, (char*)sV + dst);
    }
  };

  stage(0, half * 64);
  __syncthreads();
  int cur = 0;

  for (int j = 0; j < 16; ++j) {
    const int t = 2 * j + half;
    if (j < 15) stage(cur ^ 1, (2 * (j + 1) + half) * 64);
    const char* sKc = (const char*)sK + half * 16384 + cur * 8192;
    const char* sVc = (const char*)sV + half * 16384 + cur * 8192;

    // S^T init = additive mask rows (C-initializer; broadcast LDS reads)
    f32x16 s0, s1;
#pragma unroll
    for (int g = 0; g < 4; ++g) {
      f32x4 a0 = *(const f32x4*)(saddm + t * 64 + g * 8 + h5 * 4);
      f32x4 a1 = *(const f32x4*)(saddm + t * 64 + 32 + g * 8 + h5 * 4);
#pragma unroll
      for (int j2 = 0; j2 < 4; ++j2) { s0[g * 4 + j2] = a0[j2]; s1[g * 4 + j2] = a1[j2]; }
    }

    // S^T += K . Q (rows kv, cols q=lane)
#pragma unroll
    for (int ks = 0; ks < 4; ++ks) {
      const int sl = (((ks * 2 + h5) ^ (l31 & 7)) * 16);
      bf16x8 k0 = *(const bf16x8*)(sKc + l31 * 128 + sl);
      bf16x8 k1 = *(const bf16x8*)(sKc + (32 + l31) * 128 + sl);
      s0 = __builtin_amdgcn_mfma_f32_32x32x16_bf16(k0, qf[ks], s0, 0, 0, 0);
      s1 = __builtin_amdgcn_mfma_f32_32x32x16_bf16(k1, qf[ks], s1, 0, 0, 0);
    }

    // per-q max (log2 domain), defer-max THR=11 (~8 nats)
    f32x16 mx;
#pragma unroll
    for (int r = 0; r < 16; ++r) mx[r] = fmaxf(s0[r], s1[r]);
    float t8[8];
#pragma unroll
    for (int r = 0; r < 8; ++r) t8[r] = fmaxf(mx[r], mx[r + 8]);
    float tp = fmaxf(fmaxf(fmaxf(t8[0], t8[1]), fmaxf(t8[2], t8[3])),
                     fmaxf(fmaxf(t8[4], t8[5]), fmaxf(t8[6], t8[7])));
    {
      float ta = tp, tb = tp;
      asm("v_permlane32_swap_b32 %0, %1" : "+v"(ta), "+v"(tb));
      tp = fmaxf(ta, tb);
    }
    if (__any(tp > m_ + 11.0f)) {
      const float mnew = fmaxf(m_, tp);
      const float corr = EXP2(m_ - mnew);
      m_ = mnew;
      l_vec *= corr; o0 *= corr; o1 *= corr;
    }

    // P = 2^(S - m)
    f32x16 p0, p1;
#pragma unroll
    for (int r = 0; r < 16; ++r) p0[r] = EXP2(s0[r] - m_);
#pragma unroll
    for (int r = 0; r < 16; ++r) p1[r] = EXP2(s1[r] - m_);
    l_vec += p0; l_vec += p1;

    // P^T B-fragments in-register: cvt_pk + permlane32_swap
    bf16x8 pfs[4];
    {
      unsigned x0 = pkbf(p0[0], p0[1]), y0 = pkbf(p0[2], p0[3]);
      unsigned z0 = pkbf(p0[4], p0[5]), w0 = pkbf(p0[6], p0[7]);
      asm("v_permlane32_swap_b32 %0, %1" : "+v"(x0), "+v"(z0));
      asm("v_permlane32_swap_b32 %0, %1" : "+v"(y0), "+v"(w0));
      u32x4 f0 = {x0, y0, z0, w0};
      pfs[0] = __builtin_bit_cast(bf16x8, f0);
      unsigned x1 = pkbf(p0[8], p0[9]), y1 = pkbf(p0[10], p0[11]);
      unsigned z1 = pkbf(p0[12], p0[13]), w1 = pkbf(p0[14], p0[15]);
      asm("v_permlane32_swap_b32 %0, %1" : "+v"(x1), "+v"(z1));
      asm("v_permlane32_swap_b32 %0, %1" : "+v"(y1), "+v"(w1));
      u32x4 f1 = {x1, y1, z1, w1};
      pfs[1] = __builtin_bit_cast(bf16x8, f1);
      unsigned x2 = pkbf(p1[0], p1[1]), y2 = pkbf(p1[2], p1[3]);
      unsigned z2 = pkbf(p1[4], p1[5]), w2 = pkbf(p1[6], p1[7]);
      asm("v_permlane32_swap_b32 %0, %1" : "+v"(x2), "+v"(z2));
      asm("v_permlane32_swap_b32 %0, %1" : "+v"(y2), "+v"(w2));
      u32x4 f2 = {x2, y2, z2, w2};
      pfs[2] = __builtin_bit_cast(bf16x8, f2);
      unsigned x3 = pkbf(p1[8], p1[9]), y3 = pkbf(p1[10], p1[11]);
      unsigned z3 = pkbf(p1[12], p1[13]), w3 = pkbf(p1[14], p1[15]);
      asm("v_permlane32_swap_b32 %0, %1" : "+v"(x3), "+v"(z3));
      asm("v_permlane32_swap_b32 %0, %1" : "+v"(y3), "+v"(w3));
      u32x4 f3 = {x3, y3, z3, w3};
      pfs[3] = __builtin_bit_cast(bf16x8, f3);
    }

    // O^T += V^T . P^T
#pragma unroll
    for (int ks = 0; ks < 4; ++ks) {
      const int sl = (((ks * 2 + h5) ^ (l31 & 7)) * 16);
      bf16x8 v0 = *(const bf16x8*)(sVc + l31 * 128 + sl);
      bf16x8 v1 = *(const bf16x8*)(sVc + (32 + l31) * 128 + sl);
      o0 = __builtin_amdgcn_mfma_f32_32x32x16_bf16(v0, pfs[ks], o0, 0, 0, 0);
      o1 = __builtin_amdgcn_mfma_f32_32x32x16_bf16(v1, pfs[ks], o1, 0, 0, 0);
    }
    __syncthreads();
    cur ^= 1;
  }

  // per-half l: horizontal + cross-half-of-wave (both lanes of each q col)
  float l_part;
  {
    float a[8];
#pragma unroll
    for (int r = 0; r < 8; ++r) a[r] = l_vec[r] + l_vec[r + 8];
    l_part = ((a[0] + a[1]) + (a[2] + a[3])) + ((a[4] + a[5]) + (a[6] + a[7]));
    float ta = l_part, tb = l_part;
    asm("v_permlane32_swap_b32 %0, %1" : "+v"(ta), "+v"(tb));
    l_part = ta + tb;
  }

  // exchange (m, l) between halves; merge scales
  ex[(w * 64 + lane) * 2] = m_;
  ex[(w * 64 + lane) * 2 + 1] = l_part;
  __syncthreads();
  const int pw = w ^ 4;
  const float pm = ex[(pw * 64 + lane) * 2];
  const float plp = ex[(pw * 64 + lane) * 2 + 1];
  const float mM = fmaxf(m_, pm);
  const float lM = l_part * EXP2(m_ - mM) + plp * EXP2(pm - mM);
  const float sc = EXP2(m_ - mM) / lM;

  const float po = pl_s * 0.6931471805599453f / counts[b];
  const float wgv = 1.f / (1.f + __expf(-(po * gain[hh] + gbias[hh])));

  // co-add the two halves' O^T into the swizzled overlay
  float* sOTq = sOT + qg * 2048;
  if (half == 1) {
#pragma unroll
    for (int r = 0; r < 16; ++r) {
      const int d0 = (r & 3) + 8 * (r >> 2) + 4 * h5;
      sOTq[d0 * 32 + (l31 ^ (d0 & 31))] = o0[r] * sc;
      const int d1 = d0 + 32;
      sOTq[d1 * 32 + (l31 ^ (d1 & 31))] = o1[r] * sc;
    }
  }
  __syncthreads();
  if (half == 0) {
#pragma unroll
    for (int r = 0; r < 16; ++r) {
      const int d0 = (r & 3) + 8 * (r >> 2) + 4 * h5;
      const int i0 = d0 * 32 + (l31 ^ (d0 & 31));
      sOTq[i0] += o0[r] * sc;
      const int d1 = d0 + 32;
      const int i1 = d1 * 32 + (l31 ^ (d1 & 31));
      sOTq[i1] += o1[r] * sc;
    }
  }
  __syncthreads();

  // coalesced blend stores: wave (qg,half) covers q rows qg*32+[half*16..+16)
  const size_t rowbase = (size_t)(b * 2048 + q0 + qg * 32) * 1280 + hh * 64 + lane;
  const float* pqrow = pq + rowbase;
  float* outrow = out + rowbase;
#pragma unroll 4
  for (int i = half * 16; i < half * 16 + 16; ++i) {
    const float hval = sOTq[lane * 32 + (i ^ (lane & 31))];
    const float wgrow = __shfl(wgv, i, 64);
    const float pv = pqrow[(size_t)i * 1280];
    outrow[(size_t)i * 1280] = fmaf(hval - pv, wgrow, pv);
  }
}

// ---------- passthrough of pre_query[:, :, 1024:1280] ----------
__global__ void copy_tail(const float* __restrict__ pq, float* __restrict__ out) {
  const int idx = blockIdx.x * 256 + threadIdx.x;
  const int row = idx >> 6, c4 = idx & 63;
  const size_t off = (size_t)row * 1280 + 1024 + (size_t)c4 * 4;
  *(float4*)(out + off) = *(const float4*)(pq + off);
}

extern "C" void kernel_launch(void* const* d_in, const int* in_sizes, int n_in,
                              void* d_out, int out_size, void* d_ws, size_t ws_size,
                              hipStream_t stream) {
  const float* pre_vk = (const float*)d_in[0];
  const float* pre_q  = (const float*)d_in[1];
  const float* vmask  = (const float*)d_in[2];
  const float* vcnt   = (const float*)d_in[3];
  const float* Wq = (const float*)d_in[4];
  const float* bq = (const float*)d_in[5];
  const float* Wk = (const float*)d_in[6];
  const float* bk = (const float*)d_in[7];
  const float* Wv = (const float*)d_in[8];
  const float* bv = (const float*)d_in[9];
  const float* gain  = (const float*)d_in[10];
  const float* gbias = (const float*)d_in[11];
  float* out = (float*)d_out;

  char* ws = (char*)d_ws;
  unsigned short* pq_bf = (unsigned short*)(ws);              // 4096x1280 bf16
  unsigned short* pv_bf = (unsigned short*)(ws + 10485760);   // 4096x1024
  unsigned short* WqT   = (unsigned short*)(ws + 18874368);   // 1024x1280
  unsigned short* WkT   = (unsigned short*)(ws + 21495808);   // 1024x1024
  unsigned short* WvT   = (unsigned short*)(ws + 23592960);   // 1024x1024
  unsigned short* Qb    = (unsigned short*)(ws + 25690112);   // 4096x1024 (0.125*log2e scaled)
  unsigned short* Kbb   = (unsigned short*)(ws + 34078720);   // 4096x1024
  unsigned short* VTb   = (unsigned short*)(ws + 42467328);   // (2,16,64,2048)
  float*          kmb   = (float*)(ws + 50855936);            // (2,16,64)
  float*          addm  = (float*)(ws + 50864128);            // (2,2048)

  cvt_f32_bf16<<<5120, 256, 0, stream>>>(pre_q, pq_bf, 1310720);
  cvt_f32_bf16<<<4096, 256, 0, stream>>>(pre_vk, pv_bf, 1048576);
  transpose_w_bf16<<<dim3(32, 40), 256, 0, stream>>>(Wq, WqT, 1280, 1024);
  transpose_w_bf16<<<dim3(32, 32), 256, 0, stream>>>(Wk, WkT, 1024, 1024);
  transpose_w_bf16<<<dim3(32, 32), 256, 0, stream>>>(Wv, WvT, 1024, 1024);
  mask2addm<<<16, 256, 0, stream>>>(vmask, addm, 4096);
  gemm_all<<<dim3(32, 8, 3), 256, 0, stream>>>(pq_bf, pv_bf, WqT, WkT, WvT, bq, bk, bv, Qb, Kbb, VTb);
  km_reduce<<<32, 256, 0, stream>>>(Kbb, vmask, kmb);
  attn_fused<<<512, 512, 0, stream>>>(Qb, Kbb, VTb, addm, kmb, vcnt, gain, gbias, pre_q, out);
  copy_tail<<<1024, 256, 0, stream>>>(pre_q, out);
}

// Round 7
// 120.958 us; speedup vs baseline: 1.1793x; 1.1793x over previous
//
#include <hip/hip_runtime.h>

// ---------- types ----------
typedef __attribute__((ext_vector_type(8))) __bf16 bf16x8;
typedef __attribute__((ext_vector_type(4))) float f32x4;
typedef __attribute__((ext_vector_type(16))) float f32x16;
typedef __attribute__((ext_vector_type(4))) unsigned short us4;
typedef __attribute__((ext_vector_type(4))) unsigned int u32x4;
typedef __attribute__((address_space(3))) void* as3vp;
typedef const __attribute__((address_space(1))) void* as1vp;

#define GLOAD_LDS16(g, l) __builtin_amdgcn_global_load_lds((as1vp)(g), (as3vp)(l), 16, 0, 0)

#if __has_builtin(__builtin_amdgcn_exp2f)
#define EXP2(x) __builtin_amdgcn_exp2f(x)
#else
#define EXP2(x) __expf((x) * 0.6931471805599453f)
#endif

__device__ __forceinline__ unsigned short f2bf(float f) {
  unsigned u = __builtin_bit_cast(unsigned, f);
  u += 0x7FFFu + ((u >> 16) & 1u);   // RNE
  return (unsigned short)(u >> 16);
}
__device__ __forceinline__ float bf2f(unsigned short u) {
  return __builtin_bit_cast(float, (unsigned)u << 16);
}
__device__ __forceinline__ unsigned int pkbf(float a, float b) {
  unsigned int r;
  asm("v_cvt_pk_bf16_f32 %0, %1, %2" : "=v"(r) : "v"(a), "v"(b));
  return r;
}

// ---------- pre_q f32 -> bf16, fused with out-tail passthrough ----------
// i indexes float4 over (4096,1280). cols 1024..1279 (col4 256..319) are also
// copied straight to out (removes the separate copy_tail kernel + re-read).
__global__ void cvt_pq_tail(const float* __restrict__ x, unsigned short* __restrict__ y,
                            float* __restrict__ out) {
  const int i = blockIdx.x * 256 + threadIdx.x;
  if (i >= 1310720) return;
  float4 v = ((const float4*)x)[i];
  us4 o;
  o.x = f2bf(v.x); o.y = f2bf(v.y); o.z = f2bf(v.z); o.w = f2bf(v.w);
  ((us4*)y)[i] = o;
  if ((i % 320) >= 256) ((float4*)out)[i] = v;
}

// ---------- pre_value_key f32 -> bf16 ----------
__global__ void cvt_f32_bf16(const float* __restrict__ x, unsigned short* __restrict__ y, int n4) {
  int i = blockIdx.x * 256 + threadIdx.x;
  if (i >= n4) return;
  float4 v = ((const float4*)x)[i];
  us4 o;
  o.x = f2bf(v.x); o.y = f2bf(v.y); o.z = f2bf(v.z); o.w = f2bf(v.w);
  ((us4*)y)[i] = o;
}

// ---------- merged W (KxN f32) -> WT (NxK bf16), z selects Wq/Wk/Wv ----------
__global__ void transpose_w3(const float* __restrict__ Wq, const float* __restrict__ Wk,
                             const float* __restrict__ Wv,
                             unsigned short* __restrict__ WqT, unsigned short* __restrict__ WkT,
                             unsigned short* __restrict__ WvT) {
  const int z = blockIdx.z;
  const int K = (z == 0) ? 1280 : 1024;
  if (blockIdx.y * 32 >= (unsigned)K) return;
  const float* W = (z == 0) ? Wq : ((z == 1) ? Wk : Wv);
  unsigned short* WT = (z == 0) ? WqT : ((z == 1) ? WkT : WvT);
  __shared__ float t[32][33];
  const int tx = threadIdx.x & 31, ty = threadIdx.x >> 5;
  const int n0 = blockIdx.x * 32, k0 = blockIdx.y * 32;
#pragma unroll
  for (int i = 0; i < 32; i += 8)
    t[ty + i][tx] = W[(size_t)(k0 + ty + i) * 1024 + n0 + tx];
  __syncthreads();
#pragma unroll
  for (int i = 0; i < 32; i += 8)
    WT[(size_t)(n0 + ty + i) * K + k0 + tx] = f2bf(t[tx][ty + i]);
}

// ---------- km[b,h,d] = sum_kv mask[b,kv]*K[b,kv,h*64+d]  (256 blocks, atomic) ----------
// Also: blocks 0..15 write addm (additive mask) for attn, absorbing mask2addm.
__global__ void km_reduce(const unsigned short* __restrict__ Kbb, const float* __restrict__ mask,
                          float* __restrict__ km, float* __restrict__ addm) {
  if (blockIdx.x < 16) {
    const int i = blockIdx.x * 256 + threadIdx.x;   // 0..4095
    addm[i] = (mask[i] != 0.f) ? 0.f : -1e30f;
  }
  __shared__ float red[16][64];
  const int bh = blockIdx.x >> 3, chunk = blockIdx.x & 7;
  const int b = bh >> 4;
  const int dg = (threadIdx.x & 15) * 4, rg = threadIdx.x >> 4;
  const unsigned short* kb = Kbb + (size_t)(b * 2048) * 1024 + (bh & 15) * 64 + dg;
  const float* mr = mask + b * 2048;
  float a0 = 0.f, a1 = 0.f, a2 = 0.f, a3 = 0.f;
  const int kv0 = chunk * 256;
#pragma unroll 4
  for (int kv = kv0 + rg; kv < kv0 + 256; kv += 16) {
    const float mv = mr[kv];
    us4 kq = *(const us4*)(kb + (size_t)kv * 1024);
    a0 = fmaf(mv, bf2f(kq.x), a0); a1 = fmaf(mv, bf2f(kq.y), a1);
    a2 = fmaf(mv, bf2f(kq.z), a2); a3 = fmaf(mv, bf2f(kq.w), a3);
  }
  red[rg][dg] = a0; red[rg][dg + 1] = a1; red[rg][dg + 2] = a2; red[rg][dg + 3] = a3;
  __syncthreads();
  if (threadIdx.x < 64) {
    float s = 0.f;
#pragma unroll
    for (int i = 0; i < 16; ++i) s += red[i][threadIdx.x];
    atomicAdd(&km[bh * 64 + threadIdx.x], s);
  }
}

// ---------- merged Q/K/V GEMM, 128x128 tile (m97 geometry), dbuf single-barrier ----------
// blockIdx.z: 0=Q (KDIM 1280, scaled 0.125*log2e), 1=K, 2=V (transposed epilogue).
__global__ __launch_bounds__(256, 2)
void gemm_all(const unsigned short* __restrict__ Aq,
              const unsigned short* __restrict__ Akv,
              const unsigned short* __restrict__ WqT,
              const unsigned short* __restrict__ WkT,
              const unsigned short* __restrict__ WvT,
              const float* __restrict__ bq,
              const float* __restrict__ bk,
              const float* __restrict__ bv,
              unsigned short* __restrict__ Qout,
              unsigned short* __restrict__ Kout,
              unsigned short* __restrict__ VTout) {
  __shared__ unsigned short sA[2][128 * 64];
  __shared__ unsigned short sB[2][128 * 64];
  const int z = blockIdx.z;
  const int KDIM = (z == 0) ? 1280 : 1024;
  const unsigned short* A = (z == 0) ? Aq : Akv;
  const unsigned short* Bt = (z == 0) ? WqT : ((z == 1) ? WkT : WvT);
  const float* bias = (z == 0) ? bq : ((z == 1) ? bk : bv);

  const int tid = threadIdx.x, lane = tid & 63, w = tid >> 6;
  const int l15 = lane & 15, lhi = lane >> 4;
  const int wm = w >> 1, wn = w & 1;
  const int row0 = blockIdx.x * 128, col0 = blockIdx.y * 128;

  const f32x4 zv = {0.f, 0.f, 0.f, 0.f};
  f32x4 acc[4][4];
#pragma unroll
  for (int m = 0; m < 4; ++m)
#pragma unroll
    for (int n = 0; n < 4; ++n) acc[m][n] = zv;

  auto stage = [&](int buf, int kt) {
#pragma unroll
    for (int i = 0; i < 4; ++i) {
      const int c = i * 256 + tid;                     // 0..1023
      const int r = c >> 3, kc = ((c & 7) ^ (r & 7)) * 8;
      GLOAD_LDS16(A + (size_t)(row0 + r) * KDIM + kt + kc, &sA[buf][0] + c * 8);
      GLOAD_LDS16(Bt + (size_t)(col0 + r) * KDIM + kt + kc, &sB[buf][0] + c * 8);
    }
  };

  const int NT = KDIM / 64;
  stage(0, 0);
  __syncthreads();
  int cur = 0;
  for (int t = 0; t < NT; ++t) {
    if (t + 1 < NT) stage(cur ^ 1, (t + 1) * 64);
    const unsigned short* sAb = &sA[cur][0];
    const unsigned short* sBb = &sB[cur][0];
#pragma unroll
    for (int ks = 0; ks < 2; ++ks) {
      const int koS = (ks * 32 + lhi * 8) ^ ((l15 & 7) * 8);
      bf16x8 af[4], bfr[4];
#pragma unroll
      for (int m = 0; m < 4; ++m) af[m] = *(const bf16x8*)(sAb + (wm * 64 + m * 16 + l15) * 64 + koS);
#pragma unroll
      for (int n = 0; n < 4; ++n) bfr[n] = *(const bf16x8*)(sBb + (wn * 64 + n * 16 + l15) * 64 + koS);
#pragma unroll
      for (int m = 0; m < 4; ++m)
#pragma unroll
        for (int n = 0; n < 4; ++n)
          acc[m][n] = __builtin_amdgcn_mfma_f32_16x16x32_bf16(af[m], bfr[n], acc[m][n], 0, 0, 0);
    }
    __syncthreads();
    cur ^= 1;
  }

  if (z <= 1) {
    unsigned short* C = (z == 0) ? Qout : Kout;
    const float scale = (z == 0) ? 0.18033688f : 1.0f;   // 0.125 * log2(e)
#pragma unroll
    for (int n = 0; n < 4; ++n) {
      const int gc = col0 + wn * 64 + n * 16 + l15;
      const float bb = bias[gc];
#pragma unroll
      for (int m = 0; m < 4; ++m) {
        const int gr0 = row0 + wm * 64 + m * 16 + lhi * 4;
#pragma unroll
        for (int r = 0; r < 4; ++r)
          C[(size_t)(gr0 + r) * 1024 + gc] = f2bf((acc[m][n][r] + bb) * scale);
      }
    }
  } else {
    // V: transpose 128(rows=sv) x 128(cols=ch) tile through LDS (swz5 XOR layout),
    // coalesced 16B stores into VT (B,H,64,SV).
    __syncthreads();
    unsigned short* tb = &sA[0][0];    // 128 cols x 64 u32-words = 32 KB
#pragma unroll
    for (int n = 0; n < 4; ++n) {
      const int gcL = wn * 64 + n * 16 + l15;          // 0..127
      const float bb = bias[col0 + gcL];
      const int swz = ((gcL & 7) << 2) | ((gcL >> 3) & 1);
#pragma unroll
      for (int m = 0; m < 4; ++m) {
#pragma unroll
        for (int k = 0; k < 2; ++k) {
          const int grPair = wm * 32 + m * 8 + lhi * 2 + k;   // 0..63
          const unsigned val = pkbf(acc[m][n][2 * k] + bb, acc[m][n][2 * k + 1] + bb);
          *(unsigned*)((char*)tb + gcL * 256 + ((grPair ^ swz) * 4)) = val;
        }
      }
    }
    __syncthreads();
    const int b_ = row0 >> 11;
#pragma unroll
    for (int it = 0; it < 8; ++it) {
      const int c = it * 256 + tid;    // 0..2047
      const int gcL = c >> 4, w0 = (c & 15) * 4;
      const int swz = ((gcL & 7) << 2) | ((gcL >> 3) & 1);
      u32x4 arr = *(const u32x4*)((const char*)tb + gcL * 256 + (((w0 ^ swz) & ~3) * 4));
      const int p = swz & 3;           // in {0,1}
      u32x4 o;
      o.x = arr[0 ^ p]; o.y = arr[1 ^ p]; o.z = arr[2 ^ p]; o.w = arr[3 ^ p];
      const int ch = col0 + gcL;
      *(u32x4*)(VTout + (((size_t)(b_ * 16 + (ch >> 6))) << 17) + (size_t)(ch & 63) * 2048 +
                (row0 & 2047) + w0 * 2) = o;
    }
  }
}

// ---------- fused flash attention + pooled gate + blend (R5 structure) ----------
// 512 flat blocks (XCD-swizzled bh), 256 threads = 4 waves, 32 q-rows/wave.
// LDS-staged dbuf K/V (1 barrier/tile), swapped-operand 32x32x16 MFMA,
// in-register softmax (log2 domain), addm as MFMA C-init, km.Q pooled gate.
__global__ __launch_bounds__(256, 2)
void attn_fused(const unsigned short* __restrict__ Q,   // (B*SQ,1024) bf16, pre-scaled 0.125*log2e
                const unsigned short* __restrict__ Kb,  // (B*SV,1024) bf16
                const unsigned short* __restrict__ VT,  // (B,H,64,SV) bf16
                const float* __restrict__ addm_g,       // (B,SV) 0/-1e30
                const float* __restrict__ km,           // (B,H,64)
                const float* __restrict__ counts,       // (B)
                const float* __restrict__ gain,         // (H)
                const float* __restrict__ gbias,        // (H)
                const float* __restrict__ pq,           // (B*SQ,1280) f32
                float* __restrict__ out) {              // (B*SQ,1280) f32
  __shared__ __align__(16) char smem[40960];
  unsigned short* sK = (unsigned short*)smem;            // [2][64*64] 16 KB
  unsigned short* sV = (unsigned short*)(smem + 16384);  // [2][64*64] 16 KB
  float* saddm = (float*)(smem + 32768);                 // [2048] 8 KB
  float* sOT = (float*)smem;                             // epilogue overlay

  const int tid = threadIdx.x, lane = tid & 63, w = tid >> 6;
  const int l31 = lane & 31, h5 = lane >> 5;
  const int f = blockIdx.x;
  const int qt = (f >> 3) & 15;
  const int bh = (f & 7) + 8 * (f >> 7);
  const int b = bh >> 4, hh = bh & 15;
  const int q0 = qt * 128;

  // stage additive mask (2048 f32)
  GLOAD_LDS16(addm_g + b * 2048 + tid * 4, (char*)saddm + tid * 16);
  GLOAD_LDS16(addm_g + b * 2048 + 1024 + tid * 4, (char*)saddm + 4096 + tid * 16);

  // Q fragments (B-operand): lane l31 = q col, k = ks*16 + h5*8 + j
  bf16x8 qf[4];
  {
    const unsigned short* qp = Q + (size_t)(b * 2048 + q0 + w * 32 + l31) * 1024 + hh * 64 + h5 * 8;
#pragma unroll
    for (int ks = 0; ks < 4; ++ks) qf[ks] = *(const bf16x8*)(qp + ks * 16);
  }

  // pooled = km . q (log2-scaled; corrected by ln2 in the gate)
  float pl_s = 0.f;
  {
    const float* kmp = km + (b * 16 + hh) * 64 + h5 * 8;
#pragma unroll
    for (int ks = 0; ks < 4; ++ks) {
      f32x4 ka = *(const f32x4*)(kmp + ks * 16);
      f32x4 kb4 = *(const f32x4*)(kmp + ks * 16 + 4);
#pragma unroll
      for (int j = 0; j < 4; ++j)
        pl_s += (float)qf[ks][j] * ka[j] + (float)qf[ks][j + 4] * kb4[j];
    }
    float ta = pl_s, tb = pl_s;
    asm("v_permlane32_swap_b32 %0, %1" : "+v"(ta), "+v"(tb));
    pl_s = ta + tb;
  }

  const unsigned short* Kbase = Kb + (size_t)(b * 2048) * 1024 + hh * 64;
  const unsigned short* Vbase = VT + (((size_t)(b * 16 + hh)) << 17);

  f32x16 o0, o1, l_vec;
#pragma unroll
  for (int r = 0; r < 16; ++r) { o0[r] = 0.f; o1[r] = 0.f; l_vec[r] = 0.f; }
  float m_ = -1e30f;

  auto stage = [&](int buf, int kv) {
#pragma unroll
    for (int i = 0; i < 2; ++i) {
      const int c = i * 256 + tid;                       // 0..511
      const int r = c >> 3, sl = (c & 7) ^ (r & 7);
      GLOAD_LDS16(Kbase + (size_t)(kv + r) * 1024 + sl * 8, (char*)sK + buf * 8192 + c * 16);
      GLOAD_LDS16(Vbase + (size_t)r * 2048 + kv + sl * 8, (char*)sV + buf * 8192 + c * 16);
    }
  };

  stage(0, 0);
  __syncthreads();
  int cur = 0;

  for (int t = 0; t < 32; ++t) {
    if (t < 31) stage(cur ^ 1, (t + 1) * 64);
    const char* sKc = (const char*)sK + cur * 8192;
    const char* sVc = (const char*)sV + cur * 8192;

    // S^T init = additive mask rows (C-initializer; broadcast LDS reads)
    f32x16 s0, s1;
#pragma unroll
    for (int g = 0; g < 4; ++g) {
      f32x4 a0 = *(const f32x4*)(saddm + t * 64 + g * 8 + h5 * 4);
      f32x4 a1 = *(const f32x4*)(saddm + t * 64 + 32 + g * 8 + h5 * 4);
#pragma unroll
      for (int j = 0; j < 4; ++j) { s0[g * 4 + j] = a0[j]; s1[g * 4 + j] = a1[j]; }
    }

    // S^T += K . Q (rows kv, cols q=lane)
#pragma unroll
    for (int ks = 0; ks < 4; ++ks) {
      const int sl = (((ks * 2 + h5) ^ (l31 & 7)) * 16);
      bf16x8 k0 = *(const bf16x8*)(sKc + l31 * 128 + sl);
      bf16x8 k1 = *(const bf16x8*)(sKc + (32 + l31) * 128 + sl);
      s0 = __builtin_amdgcn_mfma_f32_32x32x16_bf16(k0, qf[ks], s0, 0, 0, 0);
      s1 = __builtin_amdgcn_mfma_f32_32x32x16_bf16(k1, qf[ks], s1, 0, 0, 0);
    }

    // wave max (log2 domain), defer-max THR=11 (~8 nats)
    f32x16 mx;
#pragma unroll
    for (int r = 0; r < 16; ++r) mx[r] = fmaxf(s0[r], s1[r]);
    float t8[8];
#pragma unroll
    for (int r = 0; r < 8; ++r) t8[r] = fmaxf(mx[r], mx[r + 8]);
    float tp = fmaxf(fmaxf(fmaxf(t8[0], t8[1]), fmaxf(t8[2], t8[3])),
                     fmaxf(fmaxf(t8[4], t8[5]), fmaxf(t8[6], t8[7])));
    {
      float ta = tp, tb = tp;
      asm("v_permlane32_swap_b32 %0, %1" : "+v"(ta), "+v"(tb));
      tp = fmaxf(ta, tb);
    }
    if (__any(tp > m_ + 11.0f)) {
      const float mnew = fmaxf(m_, tp);
      const float corr = EXP2(m_ - mnew);
      m_ = mnew;
      l_vec *= corr; o0 *= corr; o1 *= corr;
    }

    // P = 2^(S - m)
    f32x16 p0, p1;
#pragma unroll
    for (int r = 0; r < 16; ++r) p0[r] = EXP2(s0[r] - m_);
#pragma unroll
    for (int r = 0; r < 16; ++r) p1[r] = EXP2(s1[r] - m_);
    l_vec += p0; l_vec += p1;

    // P^T B-fragments in-register: cvt_pk + permlane32_swap
    bf16x8 pfs[4];
    {
      unsigned x0 = pkbf(p0[0], p0[1]), y0 = pkbf(p0[2], p0[3]);
      unsigned z0 = pkbf(p0[4], p0[5]), w0 = pkbf(p0[6], p0[7]);
      asm("v_permlane32_swap_b32 %0, %1" : "+v"(x0), "+v"(z0));
      asm("v_permlane32_swap_b32 %0, %1" : "+v"(y0), "+v"(w0));
      u32x4 f0 = {x0, y0, z0, w0};
      pfs[0] = __builtin_bit_cast(bf16x8, f0);
      unsigned x1 = pkbf(p0[8], p0[9]), y1 = pkbf(p0[10], p0[11]);
      unsigned z1 = pkbf(p0[12], p0[13]), w1 = pkbf(p0[14], p0[15]);
      asm("v_permlane32_swap_b32 %0, %1" : "+v"(x1), "+v"(z1));
      asm("v_permlane32_swap_b32 %0, %1" : "+v"(y1), "+v"(w1));
      u32x4 f1 = {x1, y1, z1, w1};
      pfs[1] = __builtin_bit_cast(bf16x8, f1);
      unsigned x2 = pkbf(p1[0], p1[1]), y2 = pkbf(p1[2], p1[3]);
      unsigned z2 = pkbf(p1[4], p1[5]), w2 = pkbf(p1[6], p1[7]);
      asm("v_permlane32_swap_b32 %0, %1" : "+v"(x2), "+v"(z2));
      asm("v_permlane32_swap_b32 %0, %1" : "+v"(y2), "+v"(w2));
      u32x4 f2 = {x2, y2, z2, w2};
      pfs[2] = __builtin_bit_cast(bf16x8, f2);
      unsigned x3 = pkbf(p1[8], p1[9]), y3 = pkbf(p1[10], p1[11]);
      unsigned z3 = pkbf(p1[12], p1[13]), w3 = pkbf(p1[14], p1[15]);
      asm("v_permlane32_swap_b32 %0, %1" : "+v"(x3), "+v"(z3));
      asm("v_permlane32_swap_b32 %0, %1" : "+v"(y3), "+v"(w3));
      u32x4 f3 = {x3, y3, z3, w3};
      pfs[3] = __builtin_bit_cast(bf16x8, f3);
    }

    // O^T += V^T . P^T
#pragma unroll
    for (int ks = 0; ks < 4; ++ks) {
      const int sl = (((ks * 2 + h5) ^ (l31 & 7)) * 16);
      bf16x8 v0 = *(const bf16x8*)(sVc + l31 * 128 + sl);
      bf16x8 v1 = *(const bf16x8*)(sVc + (32 + l31) * 128 + sl);
      o0 = __builtin_amdgcn_mfma_f32_32x32x16_bf16(v0, pfs[ks], o0, 0, 0, 0);
      o1 = __builtin_amdgcn_mfma_f32_32x32x16_bf16(v1, pfs[ks], o1, 0, 0, 0);
    }
    __syncthreads();
    cur ^= 1;
  }

  // final reductions (horizontal + cross-half)
  float l_s;
  {
    float a[8];
#pragma unroll
    for (int r = 0; r < 8; ++r) a[r] = l_vec[r] + l_vec[r + 8];
    l_s = ((a[0] + a[1]) + (a[2] + a[3])) + ((a[4] + a[5]) + (a[6] + a[7]));
    float ta = l_s, tb = l_s;
    asm("v_permlane32_swap_b32 %0, %1" : "+v"(ta), "+v"(tb));
    l_s = ta + tb;
  }
  const float po = pl_s * 0.6931471805599453f / counts[b];
  const float wgv = 1.f / (1.f + __expf(-(po * gain[hh] + gbias[hh])));
  const float invl = 1.f / l_s;

  // transpose O^T -> O through wave-private swizzled LDS overlay
  __syncthreads();
  float* myOT = sOT + w * 2048;
#pragma unroll
  for (int r = 0; r < 16; ++r) {
    const int d0 = (r & 3) + 8 * (r >> 2) + 4 * h5;
    myOT[d0 * 32 + (l31 ^ (d0 & 31))] = o0[r] * invl;
    const int d1 = d0 + 32;
    myOT[d1 * 32 + (l31 ^ (d1 & 31))] = o1[r] * invl;
  }
  __syncthreads();
  const size_t rowbase = (size_t)(b * 2048 + q0 + w * 32) * 1280 + hh * 64 + lane;
  const float* pqrow = pq + rowbase;
  float* outrow = out + rowbase;
#pragma unroll 4
  for (int i = 0; i < 32; ++i) {
    const float hval = myOT[lane * 32 + (i ^ (lane & 31))];
    const float wgrow = __shfl(wgv, i, 64);
    const float pv = pqrow[(size_t)i * 1280];
    outrow[(size_t)i * 1280] = fmaf(hval - pv, wgrow, pv);
  }
}

extern "C" void kernel_launch(void* const* d_in, const int* in_sizes, int n_in,
                              void* d_out, int out_size, void* d_ws, size_t ws_size,
                              hipStream_t stream) {
  const float* pre_vk = (const float*)d_in[0];
  const float* pre_q  = (const float*)d_in[1];
  const float* vmask  = (const float*)d_in[2];
  const float* vcnt   = (const float*)d_in[3];
  const float* Wq = (const float*)d_in[4];
  const float* bq = (const float*)d_in[5];
  const float* Wk = (const float*)d_in[6];
  const float* bk = (const float*)d_in[7];
  const float* Wv = (const float*)d_in[8];
  const float* bv = (const float*)d_in[9];
  const float* gain  = (const float*)d_in[10];
  const float* gbias = (const float*)d_in[11];
  float* out = (float*)d_out;

  char* ws = (char*)d_ws;
  unsigned short* pq_bf = (unsigned short*)(ws);              // 4096x1280 bf16
  unsigned short* pv_bf = (unsigned short*)(ws + 10485760);   // 4096x1024
  unsigned short* WqT   = (unsigned short*)(ws + 18874368);   // 1024x1280
  unsigned short* WkT   = (unsigned short*)(ws + 21495808);   // 1024x1024
  unsigned short* WvT   = (unsigned short*)(ws + 23592960);   // 1024x1024
  unsigned short* Qb    = (unsigned short*)(ws + 25690112);   // 4096x1024 (0.125*log2e scaled)
  unsigned short* Kbb   = (unsigned short*)(ws + 34078720);   // 4096x1024
  unsigned short* VTb   = (unsigned short*)(ws + 42467328);   // (2,16,64,2048)
  float*          kmb   = (float*)(ws + 50855936);            // (2,16,64)
  float*          addm  = (float*)(ws + 50864128);            // (2,2048)

  hipMemsetAsync(kmb, 0, 2 * 16 * 64 * sizeof(float), stream);
  cvt_pq_tail<<<5120, 256, 0, stream>>>(pre_q, pq_bf, out);
  cvt_f32_bf16<<<4096, 256, 0, stream>>>(pre_vk, pv_bf, 1048576);
  transpose_w3<<<dim3(32, 40, 3), 256, 0, stream>>>(Wq, Wk, Wv, WqT, WkT, WvT);
  gemm_all<<<dim3(32, 8, 3), 256, 0, stream>>>(pq_bf, pv_bf, WqT, WkT, WvT, bq, bk, bv, Qb, Kbb, VTb);
  km_reduce<<<256, 256, 0, stream>>>(Kbb, vmask, kmb, addm);
  attn_fused<<<512, 256, 0, stream>>>(Qb, Kbb, VTb, addm, kmb, vcnt, gain, gbias, pre_q, out);
}